// Round 1
// baseline (1153.738 us; speedup 1.0000x reference)
//
#include <hip/hip_runtime.h>

// ---------------------------------------------------------------------------
// Branch_62989990363328: TimesBlock conv ensemble -> TTT-MLP -> out proj
// B=2 T=400 C=64 OUT=2048 NH=8 HD=256 INNER=1024 MB=10 NC=40
// R8: Z2 allreduce via bf16 per-slice plain agent stores + gather-sum
//     (double-buffered by chunk parity; no fp32 atomics, no memset);
//     A1T/GZ1 XOR-swizzle de-conflict; W1/W2/A1 fragment register cache;
//     xk/xv prefetch split (issue in wait slot, commit late).
// ---------------------------------------------------------------------------

typedef __bf16 bf16x8 __attribute__((ext_vector_type(8)));
typedef float  f32x4  __attribute__((ext_vector_type(4)));

__device__ __forceinline__ unsigned short f2bf(float f){
  unsigned int u = __builtin_bit_cast(unsigned int, f);
  u += 0x7fffu + ((u >> 16) & 1u);
  return (unsigned short)(u >> 16);
}
__device__ __forceinline__ float bf2f(unsigned short b){
  unsigned int u = ((unsigned int)b) << 16;
  return __builtin_bit_cast(float, u);
}
__device__ __forceinline__ float gelu_f(float x){
  return 0.5f * x * (1.0f + erff(x * 0.70710678118654752f));
}
__device__ __forceinline__ float gelu_bwd_f(float x){
  return 0.5f * (1.0f + erff(x * 0.70710678118654752f))
       + x * __expf(-0.5f * x * x) * 0.3989422804014327f;
}

// ---------------------------------------------------------------------------
// Prep kernels
// ---------------------------------------------------------------------------

__global__ __launch_bounds__(256) void k_weff(
    const float* __restrict__ w0, const float* __restrict__ w1,
    const float* __restrict__ w2, const float* __restrict__ w3,
    const float* __restrict__ w4, const float* __restrict__ w5,
    unsigned short* __restrict__ weff)
{
  extern __shared__ float sw[];   // 18304 floats
  const int off[6] = {0, 64, 640, 2240, 5376, 10560};
  const float* ws6[6] = {w0, w1, w2, w3, w4, w5};
  int o = blockIdx.x, tid = threadIdx.x;
#pragma unroll
  for (int i = 0; i < 6; i++){
    int kk = 2 * i + 1, sz = 64 * kk * kk;
    const float* src = ws6[i] + (size_t)o * sz;
    for (int idx = tid; idx < sz; idx += 256) sw[off[i] + idx] = src[idx];
  }
  __syncthreads();
  for (int t = tid; t < 7744; t += 256){
    int c = t / 121, dd = t % 121, di = dd / 11, dj = dd % 11;
    float s = 0.f;
#pragma unroll
    for (int i = 0; i < 6; i++){
      int kk = 2 * i + 1;
      int a = di - 5 + i, b = dj - 5 + i;
      if (a >= 0 && a < kk && b >= 0 && b < kk)
        s += sw[off[i] + (c * kk + a) * kk + b];
    }
    weff[(size_t)o * 7744 + t] = f2bf(s);
  }
}

__global__ __launch_bounds__(256) void k_im2col(
    const float* __restrict__ x, unsigned short* __restrict__ P)
{
  int idx = blockIdx.x * 256 + threadIdx.x;
  if (idx >= 800 * 7744) return;
  int n = idx / 7744, k = idx % 7744;
  int c = k / 121, dd = k % 121, di = dd / 11, dj = dd % 11;
  int b = n / 400, pos = n % 400, i = pos / 20, j = pos % 20;
  int ii = i + di - 5, jj = j + dj - 5;
  float v = 0.f;
  if (ii >= 0 && ii < 20 && jj >= 0 && jj < 20)
    v = x[((size_t)b * 400 + ii * 20 + jj) * 64 + c];
  P[idx] = f2bf(v);
}

__global__ __launch_bounds__(256) void k_wqkv(
    const float* __restrict__ wq, const float* __restrict__ wk,
    const float* __restrict__ wv, unsigned short* __restrict__ dst)
{
  int idx = blockIdx.x * 256 + threadIdx.x;
  if (idx >= 6144 * 2048) return;
  int m = idx >> 11, kk = idx & 2047;
  const float* src = (m < 2048) ? wq : ((m < 4096) ? wk : wv);
  dst[idx] = f2bf(src[(size_t)(m & 2047) * 2048 + kk]);
}

__global__ __launch_bounds__(256) void k_f2bf_copy(
    const float* __restrict__ src, unsigned short* __restrict__ dst, int n)
{
  int idx = blockIdx.x * 256 + threadIdx.x;
  if (idx < n) dst[idx] = f2bf(src[idx]);
}

__global__ __launch_bounds__(256) void k_bsum(
    const float* __restrict__ b0, const float* __restrict__ b1,
    const float* __restrict__ b2, const float* __restrict__ b3,
    const float* __restrict__ b4, const float* __restrict__ b5,
    float* __restrict__ bsum)
{
  int idx = blockIdx.x * 256 + threadIdx.x;
  if (idx < 2048)
    bsum[idx] = b0[idx] + b1[idx] + b2[idx] + b3[idx] + b4[idx] + b5[idx];
}

__global__ __launch_bounds__(256) void k_comb_silu(
    const float* __restrict__ p0, const float* __restrict__ p1,
    const float* __restrict__ bsum, unsigned short* __restrict__ xb)
{
  int i4 = (blockIdx.x * 256 + threadIdx.x) * 4;
  float4 a = *(const float4*)&p0[i4];
  float4 b = *(const float4*)&p1[i4];
  int mm = i4 & 2047;
  float4 bs = *(const float4*)&bsum[mm];
  float v[4] = {a.x + b.x + bs.x, a.y + b.y + bs.y, a.z + b.z + bs.z, a.w + b.w + bs.w};
  ushort4 o;
#pragma unroll
  for (int i = 0; i < 4; i++){
    float t = v[i] * (1.0f / 6.0f);
    float sv = t / (1.0f + __expf(-t));
    ((unsigned short*)&o)[i] = f2bf(sv);
  }
  *(ushort4*)&xb[i4] = o;
}

__global__ __launch_bounds__(256) void k_comb_add4(
    const float* __restrict__ p, float* __restrict__ out)
{
  int i4 = (blockIdx.x * 256 + threadIdx.x) * 4;
  float4 a = *(const float4*)&p[i4];
  float4 b = *(const float4*)&p[1638400 + i4];
  float4 c = *(const float4*)&p[3276800 + i4];
  float4 d = *(const float4*)&p[4915200 + i4];
  float4 o = {a.x + b.x + c.x + d.x, a.y + b.y + c.y + d.y,
              a.z + b.z + c.z + d.z, a.w + b.w + c.w + d.w};
  *(float4*)&out[i4] = o;
}

// ---------------------------------------------------------------------------
// Generic bf16 MFMA GEMM: C[M][N] = A[M][K] * B[N][K]^T, K-split via z.
// ---------------------------------------------------------------------------
template<int MODE>
__global__ __launch_bounds__(256, 1) void k_gemm(
    const unsigned short* __restrict__ A, const unsigned short* __restrict__ B,
    int M, int N, int lda, int ldb, int kLen,
    unsigned short* __restrict__ qb, unsigned short* __restrict__ kb,
    unsigned short* __restrict__ vb, float* __restrict__ outf)
{
  __shared__ unsigned short As[128 * 32];
  __shared__ unsigned short Bs[128 * 32];
  int tid = threadIdx.x, w = tid >> 6, l = tid & 63, qd = l >> 4, lm = l & 15;
  int m0 = blockIdx.x * 128, n0 = blockIdx.y * 128;
  int kBase = blockIdx.z * kLen;

  f32x4 acc[4][4];
#pragma unroll
  for (int i = 0; i < 4; i++)
#pragma unroll
    for (int j = 0; j < 4; j++){ acc[i][j][0]=0.f; acc[i][j][1]=0.f; acc[i][j][2]=0.f; acc[i][j][3]=0.f; }

  int nk = kLen >> 5;
  for (int kt = 0; kt < nk; kt++){
    int k0 = kBase + (kt << 5);
#pragma unroll
    for (int i = 0; i < 2; i++){
      int cidx = tid + i * 256;
      int row = cidx >> 2, kc = (cidx & 3) << 3;
      *(uint4*)&As[row * 32 + kc] = *(const uint4*)&A[(size_t)(m0 + row) * lda + k0 + kc];
      int br = n0 + row; if (br >= N) br = N - 1;
      *(uint4*)&Bs[row * 32 + kc] = *(const uint4*)&B[(size_t)br * ldb + k0 + kc];
    }
    __syncthreads();
    bf16x8 af[4], bfv[4];
#pragma unroll
    for (int i = 0; i < 4; i++)
      af[i] = *(const bf16x8*)&As[((w >> 1) * 64 + i * 16 + lm) * 32 + qd * 8];
#pragma unroll
    for (int j = 0; j < 4; j++)
      bfv[j] = *(const bf16x8*)&Bs[((w & 1) * 64 + j * 16 + lm) * 32 + qd * 8];
#pragma unroll
    for (int i = 0; i < 4; i++)
#pragma unroll
      for (int j = 0; j < 4; j++)
        acc[i][j] = __builtin_amdgcn_mfma_f32_16x16x32_bf16(af[i], bfv[j], acc[i][j], 0, 0, 0);
    __syncthreads();
  }

#pragma unroll
  for (int i = 0; i < 4; i++){
    int mBase = m0 + (w >> 1) * 64 + i * 16 + qd * 4;
#pragma unroll
    for (int j = 0; j < 4; j++){
      int n = n0 + (w & 1) * 64 + j * 16 + lm;
      if (n < N){
#pragma unroll
        for (int rr = 0; rr < 4; rr++){
          float val = acc[i][j][rr];
          int mm = mBase + rr;
          if (MODE == 1){
            int proj = mm >> 11, o = mm & 2047, hh = o >> 8, d = o & 255;
            int bh = (n / 400) * 8 + hh, tt = n % 400;
            unsigned short* dst = (proj == 0) ? qb : ((proj == 1) ? kb : vb);
            dst[((size_t)bh * 400 + tt) * 256 + d] = f2bf(val);
          } else {
            outf[(size_t)blockIdx.z * M * N + (size_t)n * M + mm] = val;
          }
        }
      }
    }
  }
}

// ---------------------------------------------------------------------------
// TTT persistent kernel. 256 WGs: 16 heads x 16 INNER-slices (64 wide).
// Z2 allreduce: bf16 per-slice plain agent stores, gather-sum after barrier.
// LDS layout (ushort offsets; all b128 bases 8-aligned):
// ---------------------------------------------------------------------------
#define O_W1BT 0        // [64][264]  W1^T bf16 (inner, hd)
#define O_W2K  16896    // [64][264]  W2 bf16   (inner, hd)  - B for gZ1
#define O_W2N  33792    // [256][72]  W2^T bf16 (hd, inner)  - B for Z2
#define O_XKQ  52224    // [10][264]  xk bf16
#define O_TGT  54864    // [10][256]  (xv-xk) bf16
#define O_A1   57424    // [10][72]   A1 bf16
#define O_A1T  58144    // [64][32]   A1^T bf16, XOR-swizzled (cols>=10 zero - REQUIRED)
#define O_GZ2  60192    // [10][264]  gZ2 bf16
#define O_GZ1  62832    // [64][32]   gZ1 bf16, XOR-swizzled (cols>=10 zero - REQUIRED)
#define O_XQ2  64880    // [10][264]  xq bf16 (prev chunk's xq during fill)
#define O_GZ2T 67520    // [256][24]  gZ2^T bf16 (cols>=10 zero)
#define O_XKT  73664    // [256][24]  xk^T bf16
#define O_A1Q  79808    // [10][72]   A1q bf16 (fill phase)
#define O_F32  80528    // floats: b1s[64], b2[256]
#define O_GW   81168    // bf16[256]
#define O_GB   81424    // bf16[256]
#define US_TOTAL 81680
#define TTT_LDS_BYTES (81680 * 2)   // 163360 <= 163840

// XOR swizzle for the stride-32us [64][32] tiles: spreads the 16B fragment
// blocks of rows r, r+4, ... across all 8 bank-quads (was 4x overhead).
#define A1T_IDX(r, c) (O_A1T + ((((r) * 32) + (c)) ^ (((r) & 3) << 3)))
#define GZ1_IDX(r, c) (O_GZ1 + ((((r) * 32) + (c)) ^ (((r) & 3) << 3)))

#define ETA 0.01f
#define BAR_STRIDE 32   // 128B per head counter
#define PPAR 655360     // ushort offset between parity partial buffers

__global__ __launch_bounds__(256, 1) void k_ttt(
    const unsigned short* __restrict__ qg, const unsigned short* __restrict__ kg,
    const unsigned short* __restrict__ vg,
    const float* __restrict__ W1g, const float* __restrict__ b1g,
    const float* __restrict__ W2g, const float* __restrict__ b2g,
    const float* __restrict__ gwg, const float* __restrict__ gbg,
    unsigned short* __restrict__ part, unsigned short* __restrict__ zqp,
    unsigned int* __restrict__ bar)
{
  extern __shared__ unsigned short lds[];
  float* ldsf = (float*)&lds[O_F32];

  int tid = threadIdx.x, w = tid >> 6, l = tid & 63, qd = l >> 4, lm = l & 15;
  int bid = blockIdx.x;
  int jj = bid >> 3, xx = bid & 7;
  int h  = xx + 8 * (jj >> 4);   // bh = b*8 + head  (0..15)
  int sl = jj & 15;              // INNER slice (0..15)
  int hh = h & 7;

  for (int i = tid; i < US_TOTAL; i += 256) lds[i] = 0;
  __syncthreads();

  float w1r[4][4][4];
#pragma unroll
  for (int a = 0; a < 4; a++)
#pragma unroll
    for (int nt = 0; nt < 4; nt++)
#pragma unroll
      for (int rr = 0; rr < 4; rr++)
        w1r[a][nt][rr] = W1g[((size_t)hh * 256 + (4 * w + a) * 16 + qd * 4 + rr) * 1024
                             + sl * 64 + nt * 16 + lm];
  float w2r[16][4];
#pragma unroll
  for (int nt = 0; nt < 16; nt++)
#pragma unroll
    for (int rr = 0; rr < 4; rr++)
      w2r[nt][rr] = W2g[((size_t)hh * 1024 + sl * 64 + w * 16 + qd * 4 + rr) * 256
                        + nt * 16 + lm];
  if (tid < 64)  ldsf[tid] = b1g[hh * 1024 + sl * 64 + tid];
  if (tid < 256){
    ldsf[64 + tid] = b2g[hh * 256 + tid];
    lds[O_GW + tid] = f2bf(gwg[hh * 256 + tid]);
    lds[O_GB + tid] = f2bf(gbg[hh * 256 + tid]);
  }

#define WRITE_W1BF() do { \
  _Pragma("unroll") for (int a = 0; a < 4; a++){ \
    int m0i = (4 * w + a) * 16 + qd * 4; \
    _Pragma("unroll") for (int nt = 0; nt < 4; nt++){ \
      int n = nt * 16 + lm; \
      unsigned int p0 = f2bf(w1r[a][nt][0]) | ((unsigned int)f2bf(w1r[a][nt][1]) << 16); \
      unsigned int p1 = f2bf(w1r[a][nt][2]) | ((unsigned int)f2bf(w1r[a][nt][3]) << 16); \
      *(unsigned int*)&lds[O_W1BT + n * 264 + m0i]     = p0; \
      *(unsigned int*)&lds[O_W1BT + n * 264 + m0i + 2] = p1; \
    } } } while(0)

#define WRITE_W2BF() do { \
  int mB = w * 16 + qd * 4; \
  _Pragma("unroll") for (int nt = 0; nt < 16; nt++){ \
    int n = nt * 16 + lm; \
    _Pragma("unroll") for (int rr = 0; rr < 4; rr++) \
      lds[O_W2K + (mB + rr) * 264 + n] = f2bf(w2r[nt][rr]); \
    unsigned int p0 = f2bf(w2r[nt][0]) | ((unsigned int)f2bf(w2r[nt][1]) << 16); \
    unsigned int p1 = f2bf(w2r[nt][2]) | ((unsigned int)f2bf(w2r[nt][3]) << 16); \
    *(unsigned int*)&lds[O_W2N + n * 72 + mB]     = p0; \
    *(unsigned int*)&lds[O_W2N + n * 72 + mB + 2] = p1; \
  } } while(0)

  const size_t hb2 = (size_t)h * 400 * 256;

  unsigned int kreg[5], vreg[5];

#define LOAD_XK_REGS(NCH) do { \
  const unsigned int* kp = (const unsigned int*)(kg + hb2 + (size_t)(NCH) * 2560); \
  const unsigned int* vp = (const unsigned int*)(vg + hb2 + (size_t)(NCH) * 2560); \
  _Pragma("unroll") for (int i5 = 0; i5 < 5; i5++){ \
    kreg[i5] = kp[i5 * 256 + tid]; \
    vreg[i5] = vp[i5 * 256 + tid]; \
  } } while(0)

#define COMMIT_XK_TGT() do { \
  _Pragma("unroll") for (int i5 = 0; i5 < 5; i5++){ \
    int f2i = i5 * 256 + tid; \
    unsigned int ku = kreg[i5], vu = vreg[i5]; \
    int row = f2i >> 7, col = (f2i & 127) * 2; \
    *(unsigned int*)&lds[O_XKQ + row * 264 + col] = ku; \
    lds[O_XKT + col * 24 + row]       = (unsigned short)(ku & 0xffffu); \
    lds[O_XKT + (col + 1) * 24 + row] = (unsigned short)(ku >> 16); \
    float kv0 = bf2f((unsigned short)(ku & 0xffffu)), kv1 = bf2f((unsigned short)(ku >> 16)); \
    float vv0 = bf2f((unsigned short)(vu & 0xffffu)), vv1 = bf2f((unsigned short)(vu >> 16)); \
    unsigned int tu = (unsigned int)f2bf(vv0 - kv0) | ((unsigned int)f2bf(vv1 - kv1) << 16); \
    *(unsigned int*)&lds[O_TGT + row * 256 + col] = tu; \
  } } while(0)

#define LOAD_XQ(NCH) do { \
  const unsigned int* qp = (const unsigned int*)(qg + hb2 + (size_t)(NCH) * 2560); \
  _Pragma("unroll") for (int i5 = 0; i5 < 5; i5++){ \
    int f2i = i5 * 256 + tid; \
    unsigned int qu = qp[f2i]; \
    int row = f2i >> 7, col = (f2i & 127) * 2; \
    *(unsigned int*)&lds[O_XQ2 + row * 264 + col] = qu; \
  } } while(0)

  WRITE_W1BF();
  WRITE_W2BF();
  LOAD_XK_REGS(0);
  COMMIT_XK_TGT();
  LOAD_XQ(0);
  __syncthreads();

  for (int nch = 0; nch < 40; nch++){
    // W1^T / b1 fragments for this chunk's weights (reused by the query fill)
    bf16x8 w1f[8];
#pragma unroll
    for (int ks = 0; ks < 8; ks++)
      w1f[ks] = *(const bf16x8*)&lds[O_W1BT + (w * 16 + lm) * 264 + ks * 32 + qd * 8];
    float b1n = ldsf[w * 16 + lm];

    // 1. Z1 = xk@W1 + b1 -> A1 (uses W_{nch-1})
    f32x4 z1a; z1a[0]=0.f; z1a[1]=0.f; z1a[2]=0.f; z1a[3]=0.f;
#pragma unroll
    for (int ks = 0; ks < 8; ks++){
      bf16x8 av = *(const bf16x8*)&lds[O_XKQ + lm * 264 + ks * 32 + qd * 8];
      z1a = __builtin_amdgcn_mfma_f32_16x16x32_bf16(av, w1f[ks], z1a, 0, 0, 0);
    }
    float z1v[4];
#pragma unroll
    for (int rr = 0; rr < 4; rr++){
      z1v[rr] = z1a[rr] + b1n;
      int mr = qd * 4 + rr;
      if (mr < 10){
        float a1 = gelu_f(z1v[rr]);
        unsigned short ab = f2bf(a1);
        lds[O_A1 + mr * 72 + w * 16 + lm] = ab;
        lds[A1T_IDX(w * 16 + lm, mr)] = ab;
      }
    }
    __syncthreads();

    // 3. Z2 partial = A1@W2 -> bf16 plain stores to this slice's slot
    //    (parity double-buffer kills the cross-chunk writer/reader race)
    bf16x8 a1f[2], w2f[4][2];
#pragma unroll
    for (int ks = 0; ks < 2; ks++)
      a1f[ks] = *(const bf16x8*)&lds[O_A1 + lm * 72 + ks * 32 + qd * 8];
#pragma unroll
    for (int nt4 = 0; nt4 < 4; nt4++)
#pragma unroll
      for (int ks = 0; ks < 2; ks++)
        w2f[nt4][ks] = *(const bf16x8*)&lds[O_W2N + ((4 * w + nt4) * 16 + lm) * 72 + ks * 32 + qd * 8];

    {
      unsigned short* pslot = part + ((nch & 1) ? PPAR : 0) + (size_t)(h * 16 + sl) * 2560;
#pragma unroll
      for (int nt4 = 0; nt4 < 4; nt4++){
        int nt = 4 * w + nt4;
        f32x4 p; p[0]=0.f; p[1]=0.f; p[2]=0.f; p[3]=0.f;
#pragma unroll
        for (int ks = 0; ks < 2; ks++)
          p = __builtin_amdgcn_mfma_f32_16x16x32_bf16(a1f[ks], w2f[nt4][ks], p, 0, 0, 0);
#pragma unroll
        for (int rr = 0; rr < 4; rr++){
          int mr = qd * 4 + rr;
          if (mr < 10)
            __hip_atomic_store(&pslot[mr * 256 + nt * 16 + lm], f2bf(p[rr]),
                               __ATOMIC_RELAXED, __HIP_MEMORY_SCOPE_AGENT);
        }
      }
    }
    __syncthreads();   // drain partial stores (vmcnt0 before bar add)

    // 5. barrier add, then FILL the wait slot with prev chunk's query outputs
    if (tid == 0)
      __hip_atomic_fetch_add(bar + h * BAR_STRIDE, 1u, __ATOMIC_RELAXED, __HIP_MEMORY_SCOPE_AGENT);

    // issue next chunk's xk/xv global loads early (commit to LDS much later)
    if (nch + 1 < 40)
      LOAD_XK_REGS(nch + 1);

    if (nch > 0){
      // Z1q_{nch-1} = xq_{nch-1}@W1_{nch-1} + b1_{nch-1} -> A1q  (w1f = W_{nch-1})
      f32x4 zq; zq[0]=0.f; zq[1]=0.f; zq[2]=0.f; zq[3]=0.f;
#pragma unroll
      for (int ks = 0; ks < 8; ks++){
        bf16x8 av = *(const bf16x8*)&lds[O_XQ2 + lm * 264 + ks * 32 + qd * 8];
        zq = __builtin_amdgcn_mfma_f32_16x16x32_bf16(av, w1f[ks], zq, 0, 0, 0);
      }
#pragma unroll
      for (int rr = 0; rr < 4; rr++){
        int mr = qd * 4 + rr;
        if (mr < 10)
          lds[O_A1Q + mr * 72 + w * 16 + lm] = f2bf(gelu_f(zq[rr] + b1n));
      }
    }
    __syncthreads();   // A1Q visible; XQ2 free

    if (nch > 0){
      LOAD_XQ(nch);    // overwrite with current chunk's xq (for next fill)
      // Z2q partial = A1q@W2_{nch-1} -> bf16 store (chunk nch-1); w2f reused
      unsigned short* zq_out = zqp + ((size_t)(h * 16 + sl) * 40 + (nch - 1)) * 2560;
      bf16x8 a1qf[2];
#pragma unroll
      for (int ks = 0; ks < 2; ks++)
        a1qf[ks] = *(const bf16x8*)&lds[O_A1Q + lm * 72 + ks * 32 + qd * 8];
#pragma unroll
      for (int nt4 = 0; nt4 < 4; nt4++){
        int nt = 4 * w + nt4;
        f32x4 p; p[0]=0.f; p[1]=0.f; p[2]=0.f; p[3]=0.f;
#pragma unroll
        for (int ks = 0; ks < 2; ks++)
          p = __builtin_amdgcn_mfma_f32_16x16x32_bf16(a1qf[ks], w2f[nt4][ks], p, 0, 0, 0);
        float bb = (sl == 0) ? ldsf[64 + nt * 16 + lm] : 0.f;
#pragma unroll
        for (int rr = 0; rr < 4; rr++){
          int mr = qd * 4 + rr;
          if (mr < 10)
            zq_out[mr * 256 + nt * 16 + lm] = f2bf(p[rr] + bb);
        }
      }
    }

    // 6. poll (after fill — wait time absorbed by the fill work above)
    if (tid == 0){
      unsigned int target = 16u * (unsigned int)(nch + 1);
      unsigned int spins = 0;
      while (__hip_atomic_load(bar + h * BAR_STRIDE, __ATOMIC_RELAXED, __HIP_MEMORY_SCOPE_AGENT) < target
             && spins < 8000000u){ spins++; __builtin_amdgcn_s_sleep(1); }
    }
    __syncthreads();

    // 7. gather the 16 bf16 slice partials, reduce in f32, fused LN-L2 backward
    {
      const unsigned long long* pb = (const unsigned long long*)
          (part + ((nch & 1) ? PPAR : 0) + (size_t)h * 16 * 2560);
      for (int r2 = w; r2 < 10; r2 += 4){
        int c0 = l * 4;
        float zz[4];
#pragma unroll
        for (int i = 0; i < 4; i++) zz[i] = ldsf[64 + c0 + i];   // + b2
#pragma unroll
        for (int s16 = 0; s16 < 16; s16++){
          unsigned long long u = __hip_atomic_load(&pb[(size_t)s16 * 640 + r2 * 64 + l],
                                                   __ATOMIC_RELAXED, __HIP_MEMORY_SCOPE_AGENT);
          zz[0] += bf2f((unsigned short)(u & 0xffffu));
          zz[1] += bf2f((unsigned short)((u >> 16) & 0xffffu));
          zz[2] += bf2f((unsigned short)((u >> 32) & 0xffffu));
          zz[3] += bf2f((unsigned short)(u >> 48));
        }
        float s1 = 0.f, s2 = 0.f;
#pragma unroll
        for (int i = 0; i < 4; i++){ s1 += zz[i]; s2 += zz[i] * zz[i]; }
#pragma unroll
        for (int off = 32; off >= 1; off >>= 1){ s1 += __shfl_xor(s1, off, 64); s2 += __shfl_xor(s2, off, 64); }
        float mu = s1 * (1.f / 256.f);
        float var = s2 * (1.f / 256.f) - mu * mu;
        float rstd = rsqrtf(var + 1e-6f);
        float xh[4], gx[4];
        float t1 = 0.f, t2 = 0.f;
#pragma unroll
        for (int i = 0; i < 4; i++){
          xh[i] = (zz[i] - mu) * rstd;
          float gwv = bf2f(lds[O_GW + c0 + i]), gbv = bf2f(lds[O_GB + c0 + i]);
          float tg = bf2f(lds[O_TGT + r2 * 256 + c0 + i]);
          float go = gwv * xh[i] + gbv - tg;
          gx[i] = go * gwv;
          t1 += gx[i]; t2 += gx[i] * xh[i];
        }
#pragma unroll
        for (int off = 32; off >= 1; off >>= 1){ t1 += __shfl_xor(t1, off, 64); t2 += __shfl_xor(t2, off, 64); }
        float m1 = t1 * (1.f / 256.f), m2 = t2 * (1.f / 256.f);
        float g0 = (gx[0] - m1 - xh[0] * m2) * rstd;
        float g1 = (gx[1] - m1 - xh[1] * m2) * rstd;
        float g2 = (gx[2] - m1 - xh[2] * m2) * rstd;
        float g3 = (gx[3] - m1 - xh[3] * m2) * rstd;
        unsigned int p0 = f2bf(g0) | ((unsigned int)f2bf(g1) << 16);
        unsigned int p1 = f2bf(g2) | ((unsigned int)f2bf(g3) << 16);
        *(unsigned int*)&lds[O_GZ2 + r2 * 264 + c0]     = p0;
        *(unsigned int*)&lds[O_GZ2 + r2 * 264 + c0 + 2] = p1;
      }
    }
    __syncthreads();

    // 9a. b2 -= eta * sum_rows(gZ2); build gZ2^T
    {
      float sum = 0.f;
#pragma unroll
      for (int r2 = 0; r2 < 10; r2++){
        unsigned short g = lds[O_GZ2 + r2 * 264 + tid];
        lds[O_GZ2T + tid * 24 + r2] = g;
        sum += bf2f(g);
      }
      ldsf[64 + tid] -= ETA * sum;
    }
    // 9b. gZ1 = (gZ2 @ W2^T) * gelu'(Z1)
    {
      f32x4 g1a; g1a[0]=0.f; g1a[1]=0.f; g1a[2]=0.f; g1a[3]=0.f;
#pragma unroll
      for (int ks = 0; ks < 8; ks++){
        bf16x8 av = *(const bf16x8*)&lds[O_GZ2 + lm * 264 + ks * 32 + qd * 8];
        bf16x8 bv = *(const bf16x8*)&lds[O_W2K + (w * 16 + lm) * 264 + ks * 32 + qd * 8];
        g1a = __builtin_amdgcn_mfma_f32_16x16x32_bf16(av, bv, g1a, 0, 0, 0);
      }
#pragma unroll
      for (int rr = 0; rr < 4; rr++){
        int mr = qd * 4 + rr;
        if (mr < 10){
          float gz1 = g1a[rr] * gelu_bwd_f(z1v[rr]);
          lds[GZ1_IDX(w * 16 + lm, mr)] = f2bf(gz1);
        }
      }
    }
    __syncthreads();

    // 11a. b1 -= eta * colsum(gZ1)
    if (tid < 64){
      float sum = 0.f;
#pragma unroll
      for (int kx = 0; kx < 10; kx++) sum += bf2f(lds[GZ1_IDX(tid, kx)]);
      ldsf[tid] -= ETA * sum;
    }
    // 11b. W1 update: dW1 = xk^T @ gZ1
#pragma unroll
    for (int a = 0; a < 4; a++){
      int mt = 4 * w + a;
      bf16x8 av = *(const bf16x8*)&lds[O_XKT + (mt * 16 + lm) * 24 + (qd & 1) * 8];
#pragma unroll
      for (int nt = 0; nt < 4; nt++){
        bf16x8 bv = *(const bf16x8*)&lds[GZ1_IDX(nt * 16 + lm, qd * 8)];
        f32x4 d; d[0]=0.f; d[1]=0.f; d[2]=0.f; d[3]=0.f;
        d = __builtin_amdgcn_mfma_f32_16x16x32_bf16(av, bv, d, 0, 0, 0);
#pragma unroll
        for (int rr = 0; rr < 4; rr++) w1r[a][nt][rr] -= ETA * d[rr];
      }
    }
    // 11c. W2 update: dW2 = A1^T @ gZ2
    {
      bf16x8 av2 = *(const bf16x8*)&lds[A1T_IDX(w * 16 + lm, qd * 8)];
#pragma unroll
      for (int nt = 0; nt < 16; nt++){
        bf16x8 bv = *(const bf16x8*)&lds[O_GZ2T + (nt * 16 + lm) * 24 + (qd & 1) * 8];
        f32x4 d; d[0]=0.f; d[1]=0.f; d[2]=0.f; d[3]=0.f;
        d = __builtin_amdgcn_mfma_f32_16x16x32_bf16(av2, bv, d, 0, 0, 0);
#pragma unroll
        for (int rr = 0; rr < 4; rr++) w2r[nt][rr] -= ETA * d[rr];
      }
    }
    WRITE_W1BF();
    WRITE_W2BF();
    __syncthreads();

    // commit next chunk's xk/tgt (loads were issued back in the wait slot)
    if (nch + 1 < 40){
      COMMIT_XK_TGT();
    }
    __syncthreads();
  }

  // epilogue: query outputs for chunk 39 (W1BT/W2N = W_39, XQ2 = xq_39)
  {
    f32x4 zq; zq[0]=0.f; zq[1]=0.f; zq[2]=0.f; zq[3]=0.f;
#pragma unroll
    for (int ks = 0; ks < 8; ks++){
      bf16x8 av = *(const bf16x8*)&lds[O_XQ2 + lm * 264 + ks * 32 + qd * 8];
      bf16x8 bv = *(const bf16x8*)&lds[O_W1BT + (w * 16 + lm) * 264 + ks * 32 + qd * 8];
      zq = __builtin_amdgcn_mfma_f32_16x16x32_bf16(av, bv, zq, 0, 0, 0);
    }
    float b1n = ldsf[w * 16 + lm];
#pragma unroll
    for (int rr = 0; rr < 4; rr++){
      int mr = qd * 4 + rr;
      if (mr < 10)
        lds[O_A1Q + mr * 72 + w * 16 + lm] = f2bf(gelu_f(zq[rr] + b1n));
    }
  }
  __syncthreads();
  {
    unsigned short* zq_out = zqp + ((size_t)(h * 16 + sl) * 40 + 39) * 2560;
#pragma unroll
    for (int nt4 = 0; nt4 < 4; nt4++){
      int nt = 4 * w + nt4;
      f32x4 p; p[0]=0.f; p[1]=0.f; p[2]=0.f; p[3]=0.f;
#pragma unroll
      for (int ks = 0; ks < 2; ks++){
        bf16x8 av = *(const bf16x8*)&lds[O_A1Q + lm * 72 + ks * 32 + qd * 8];
        bf16x8 bv = *(const bf16x8*)&lds[O_W2N + (nt * 16 + lm) * 72 + ks * 32 + qd * 8];
        p = __builtin_amdgcn_mfma_f32_16x16x32_bf16(av, bv, p, 0, 0, 0);
      }
      float bb = (sl == 0) ? ldsf[64 + nt * 16 + lm] : 0.f;
#pragma unroll
      for (int rr = 0; rr < 4; rr++){
        int mr = qd * 4 + rr;
        if (mr < 10)
          zq_out[mr * 256 + nt * 16 + lm] = f2bf(p[rr] + bb);
      }
    }
  }
}

// ---------------------------------------------------------------------------
// LN forward + residual; sums 16 bf16 slice partials of Z2q in fp32.
// ---------------------------------------------------------------------------
__global__ __launch_bounds__(256) void k_lnout(
    const unsigned short* __restrict__ zqp, const unsigned short* __restrict__ qg,
    const float* __restrict__ gwg, const float* __restrict__ gbg,
    unsigned short* __restrict__ obf)
{
  int w = threadIdx.x >> 6, l = threadIdx.x & 63;
  int gr = blockIdx.x * 4 + w;
  int h = gr / 400, t = gr % 400, hh = h & 7, b = h >> 3;
  int nch = t / 10, mr = t % 10;
  int c0 = l * 4;
  float z[4] = {0.f, 0.f, 0.f, 0.f};
#pragma unroll
  for (int sl = 0; sl < 16; sl++){
    const unsigned short* zp = zqp + (((size_t)(h * 16 + sl) * 40 + nch) * 10 + mr) * 256 + c0;
    ushort4 u = *(const ushort4*)zp;
    z[0] += bf2f(u.x); z[1] += bf2f(u.y); z[2] += bf2f(u.z); z[3] += bf2f(u.w);
  }
  float s1 = 0.f, s2 = 0.f;
#pragma unroll
  for (int i = 0; i < 4; i++){ s1 += z[i]; s2 += z[i] * z[i]; }
#pragma unroll
  for (int off = 32; off >= 1; off >>= 1){ s1 += __shfl_xor(s1, off, 64); s2 += __shfl_xor(s2, off, 64); }
  float mu = s1 * (1.f / 256.f);
  float var = s2 * (1.f / 256.f) - mu * mu;
  float rstd = rsqrtf(var + 1e-6f);
  const unsigned short* qp = &qg[((size_t)h * 400 + t) * 256];
  ushort4 qu = *(const ushort4*)&qp[c0];
  float qv[4] = {bf2f(qu.x), bf2f(qu.y), bf2f(qu.z), bf2f(qu.w)};
  unsigned short* op = &obf[((size_t)(b * 400 + t)) * 2048 + hh * 256];
#pragma unroll
  for (int i = 0; i < 4; i++){
    float xh = (z[i] - mu) * rstd;
    float o = qv[i] + gwg[hh * 256 + c0 + i] * xh + gbg[hh * 256 + c0 + i];
    op[c0 + i] = f2bf(o);
  }
}

// ---------------------------------------------------------------------------
// launch — workspace map (bytes)
// ---------------------------------------------------------------------------
#define WS_WEFF   0u          // weff (dead after gemm0) | zqp 52.4MB | g2part 26.2MB (post-lnout)
#define WS_P      31719424u
#define WS_WQKV   44109824u
#define WS_WOB    52428800u
#define WS_Z2ACC  62722048u   // bf16 Z2 slice partials, 2 parity buffers (2.62MB)
#define WS_XB     69275648u
#define WS_Q      72552448u   // | g0part 13.1MB (pre-gemm1)
#define WS_K      75829248u
#define WS_V      79106048u
#define WS_OBF    82382848u
#define WS_BSUM   85659648u
#define WS_BAR    85667840u

extern "C" void kernel_launch(void* const* d_in, const int* in_sizes, int n_in,
                              void* d_out, int out_size, void* d_ws, size_t ws_size,
                              hipStream_t stream)
{
  (void)in_sizes; (void)n_in; (void)out_size; (void)ws_size;
  const float* x  = (const float*)d_in[0];
  const float* cw[6]; const float* cb[6];
  for (int i = 0; i < 6; i++){ cw[i] = (const float*)d_in[2 + 2 * i]; cb[i] = (const float*)d_in[3 + 2 * i]; }
  const float* wq  = (const float*)d_in[14];
  const float* wk  = (const float*)d_in[15];
  const float* wv  = (const float*)d_in[16];
  const float* wo  = (const float*)d_in[17];
  const float* W1  = (const float*)d_in[18];
  const float* b1  = (const float*)d_in[19];
  const float* W2  = (const float*)d_in[20];
  const float* b2  = (const float*)d_in[21];
  const float* lnw = (const float*)d_in[22];
  const float* lnb = (const float*)d_in[23];
  float* outf = (float*)d_out;

  char* wsb = (char*)d_ws;
  unsigned short* weff = (unsigned short*)(wsb + WS_WEFF);
  unsigned short* P    = (unsigned short*)(wsb + WS_P);
  unsigned short* wqkv = (unsigned short*)(wsb + WS_WQKV);
  unsigned short* wob  = (unsigned short*)(wsb + WS_WOB);
  unsigned short* xb   = (unsigned short*)(wsb + WS_XB);
  unsigned short* qb   = (unsigned short*)(wsb + WS_Q);
  unsigned short* kb   = (unsigned short*)(wsb + WS_K);
  unsigned short* vb   = (unsigned short*)(wsb + WS_V);
  unsigned short* part = (unsigned short*)(wsb + WS_Z2ACC);
  unsigned short* zqp = (unsigned short*)(wsb + WS_WEFF);
  unsigned short* obf = (unsigned short*)(wsb + WS_OBF);
  float* bsum = (float*)(wsb + WS_BSUM);
  unsigned int* bar = (unsigned int*)(wsb + WS_BAR);
  float* g0part = (float*)(wsb + WS_Q);      // pre-gemm1
  float* g2part = (float*)(wsb + WS_WEFF);   // post-lnout (zqp dead), 26.2MB

  hipMemsetAsync(bar, 0, 16 * BAR_STRIDE * 4, stream);
  hipFuncSetAttribute(reinterpret_cast<const void*>(k_ttt),
                      hipFuncAttributeMaxDynamicSharedMemorySize, TTT_LDS_BYTES);
  hipFuncSetAttribute(reinterpret_cast<const void*>(k_weff),
                      hipFuncAttributeMaxDynamicSharedMemorySize, 18304 * 4);

  k_weff<<<2048, 256, 18304 * 4, stream>>>(cw[0], cw[1], cw[2], cw[3], cw[4], cw[5], weff);
  k_im2col<<<(800 * 7744 + 255) / 256, 256, 0, stream>>>(x, P);
  k_wqkv<<<(6144 * 2048 + 255) / 256, 256, 0, stream>>>(wq, wk, wv, wqkv);
  k_bsum<<<8, 256, 0, stream>>>(cb[0], cb[1], cb[2], cb[3], cb[4], cb[5], bsum);

  k_gemm<2><<<dim3(16, 7, 2), 256, 0, stream>>>(weff, P, 2048, 800, 7744, 7744, 3872,
                                                nullptr, nullptr, nullptr, g0part);
  k_comb_silu<<<1600, 256, 0, stream>>>(g0part, g0part + 1638400, bsum, xb);

  k_gemm<1><<<dim3(48, 7, 1), 256, 0, stream>>>(wqkv, xb, 6144, 800, 2048, 2048, 2048,
                                                qb, kb, vb, nullptr);

  k_f2bf_copy<<<(2048 * 2048 + 255) / 256, 256, 0, stream>>>(wo, wob, 2048 * 2048);

  k_ttt<<<256, 256, TTT_LDS_BYTES, stream>>>(qb, kb, vb, W1, b1, W2, b2, lnw, lnb,
                                             part, zqp, bar);
  k_lnout<<<1600, 256, 0, stream>>>(zqp, qb, lnw, lnb, obf);

  k_gemm<2><<<dim3(16, 7, 4), 256, 0, stream>>>(wob, obf, 2048, 800, 2048, 2048, 512,
                                                nullptr, nullptr, nullptr, g2part);
  k_comb_add4<<<1600, 256, 0, stream>>>(g2part, outf);
}

// Round 2
// 1032.579 us; speedup vs baseline: 1.1173x; 1.1173x over previous
//
#include <hip/hip_runtime.h>

// ---------------------------------------------------------------------------
// Branch_62989990363328: TimesBlock conv ensemble -> TTT-MLP -> out proj
// B=2 T=400 C=64 OUT=2048 NH=8 HD=256 INNER=1024 MB=10 NC=40
// R9: allreduce reverted to fp32 atomicAdd + reduced-value readback (R8's
//     redundant 16x bf16 gather cost +100us in uncached reads). Kept from R8:
//     A1T/GZ1 XOR-swizzle, W1/W2/A1 fragment register cache, split xk/xv
//     prefetch. k_bsum folded into k_weff (launch elimination).
// ---------------------------------------------------------------------------

typedef __bf16 bf16x8 __attribute__((ext_vector_type(8)));
typedef float  f32x4  __attribute__((ext_vector_type(4)));

__device__ __forceinline__ unsigned short f2bf(float f){
  unsigned int u = __builtin_bit_cast(unsigned int, f);
  u += 0x7fffu + ((u >> 16) & 1u);
  return (unsigned short)(u >> 16);
}
__device__ __forceinline__ float bf2f(unsigned short b){
  unsigned int u = ((unsigned int)b) << 16;
  return __builtin_bit_cast(float, u);
}
__device__ __forceinline__ float gelu_f(float x){
  return 0.5f * x * (1.0f + erff(x * 0.70710678118654752f));
}
__device__ __forceinline__ float gelu_bwd_f(float x){
  return 0.5f * (1.0f + erff(x * 0.70710678118654752f))
       + x * __expf(-0.5f * x * x) * 0.3989422804014327f;
}

// agent-scope relaxed atomic helpers (MALL-coherent, bypass L1/L2)
__device__ __forceinline__ float2 aload2(const float* p){
  unsigned long long v = __hip_atomic_load((const unsigned long long*)p,
                                           __ATOMIC_RELAXED, __HIP_MEMORY_SCOPE_AGENT);
  union { unsigned long long u; float2 f; } cv; cv.u = v; return cv.f;
}
__device__ __forceinline__ void aadd(float* p, float v){
  __hip_atomic_fetch_add(p, v, __ATOMIC_RELAXED, __HIP_MEMORY_SCOPE_AGENT);
}

// ---------------------------------------------------------------------------
// Prep kernels
// ---------------------------------------------------------------------------

__global__ __launch_bounds__(256) void k_weff(
    const float* __restrict__ w0, const float* __restrict__ w1,
    const float* __restrict__ w2, const float* __restrict__ w3,
    const float* __restrict__ w4, const float* __restrict__ w5,
    const float* __restrict__ b0, const float* __restrict__ b1,
    const float* __restrict__ b2, const float* __restrict__ b3,
    const float* __restrict__ b4, const float* __restrict__ b5,
    unsigned short* __restrict__ weff, float* __restrict__ bsum)
{
  extern __shared__ float sw[];   // 18304 floats
  const int off[6] = {0, 64, 640, 2240, 5376, 10560};
  const float* ws6[6] = {w0, w1, w2, w3, w4, w5};
  int o = blockIdx.x, tid = threadIdx.x;
  if (tid == 0)
    bsum[o] = b0[o] + b1[o] + b2[o] + b3[o] + b4[o] + b5[o];
#pragma unroll
  for (int i = 0; i < 6; i++){
    int kk = 2 * i + 1, sz = 64 * kk * kk;
    const float* src = ws6[i] + (size_t)o * sz;
    for (int idx = tid; idx < sz; idx += 256) sw[off[i] + idx] = src[idx];
  }
  __syncthreads();
  for (int t = tid; t < 7744; t += 256){
    int c = t / 121, dd = t % 121, di = dd / 11, dj = dd % 11;
    float s = 0.f;
#pragma unroll
    for (int i = 0; i < 6; i++){
      int kk = 2 * i + 1;
      int a = di - 5 + i, b = dj - 5 + i;
      if (a >= 0 && a < kk && b >= 0 && b < kk)
        s += sw[off[i] + (c * kk + a) * kk + b];
    }
    weff[(size_t)o * 7744 + t] = f2bf(s);
  }
}

__global__ __launch_bounds__(256) void k_im2col(
    const float* __restrict__ x, unsigned short* __restrict__ P)
{
  int idx = blockIdx.x * 256 + threadIdx.x;
  if (idx >= 800 * 7744) return;
  int n = idx / 7744, k = idx % 7744;
  int c = k / 121, dd = k % 121, di = dd / 11, dj = dd % 11;
  int b = n / 400, pos = n % 400, i = pos / 20, j = pos % 20;
  int ii = i + di - 5, jj = j + dj - 5;
  float v = 0.f;
  if (ii >= 0 && ii < 20 && jj >= 0 && jj < 20)
    v = x[((size_t)b * 400 + ii * 20 + jj) * 64 + c];
  P[idx] = f2bf(v);
}

__global__ __launch_bounds__(256) void k_wqkv(
    const float* __restrict__ wq, const float* __restrict__ wk,
    const float* __restrict__ wv, unsigned short* __restrict__ dst)
{
  int idx = blockIdx.x * 256 + threadIdx.x;
  if (idx >= 6144 * 2048) return;
  int m = idx >> 11, kk = idx & 2047;
  const float* src = (m < 2048) ? wq : ((m < 4096) ? wk : wv);
  dst[idx] = f2bf(src[(size_t)(m & 2047) * 2048 + kk]);
}

__global__ __launch_bounds__(256) void k_f2bf_copy(
    const float* __restrict__ src, unsigned short* __restrict__ dst, int n)
{
  int idx = blockIdx.x * 256 + threadIdx.x;
  if (idx < n) dst[idx] = f2bf(src[idx]);
}

__global__ __launch_bounds__(256) void k_comb_silu(
    const float* __restrict__ p0, const float* __restrict__ p1,
    const float* __restrict__ bsum, unsigned short* __restrict__ xb)
{
  int i4 = (blockIdx.x * 256 + threadIdx.x) * 4;
  float4 a = *(const float4*)&p0[i4];
  float4 b = *(const float4*)&p1[i4];
  int mm = i4 & 2047;
  float4 bs = *(const float4*)&bsum[mm];
  float v[4] = {a.x + b.x + bs.x, a.y + b.y + bs.y, a.z + b.z + bs.z, a.w + b.w + bs.w};
  ushort4 o;
#pragma unroll
  for (int i = 0; i < 4; i++){
    float t = v[i] * (1.0f / 6.0f);
    float sv = t / (1.0f + __expf(-t));
    ((unsigned short*)&o)[i] = f2bf(sv);
  }
  *(ushort4*)&xb[i4] = o;
}

__global__ __launch_bounds__(256) void k_comb_add4(
    const float* __restrict__ p, float* __restrict__ out)
{
  int i4 = (blockIdx.x * 256 + threadIdx.x) * 4;
  float4 a = *(const float4*)&p[i4];
  float4 b = *(const float4*)&p[1638400 + i4];
  float4 c = *(const float4*)&p[3276800 + i4];
  float4 d = *(const float4*)&p[4915200 + i4];
  float4 o = {a.x + b.x + c.x + d.x, a.y + b.y + c.y + d.y,
              a.z + b.z + c.z + d.z, a.w + b.w + c.w + d.w};
  *(float4*)&out[i4] = o;
}

// ---------------------------------------------------------------------------
// Generic bf16 MFMA GEMM: C[M][N] = A[M][K] * B[N][K]^T, K-split via z.
// ---------------------------------------------------------------------------
template<int MODE>
__global__ __launch_bounds__(256, 1) void k_gemm(
    const unsigned short* __restrict__ A, const unsigned short* __restrict__ B,
    int M, int N, int lda, int ldb, int kLen,
    unsigned short* __restrict__ qb, unsigned short* __restrict__ kb,
    unsigned short* __restrict__ vb, float* __restrict__ outf)
{
  __shared__ unsigned short As[128 * 32];
  __shared__ unsigned short Bs[128 * 32];
  int tid = threadIdx.x, w = tid >> 6, l = tid & 63, qd = l >> 4, lm = l & 15;
  int m0 = blockIdx.x * 128, n0 = blockIdx.y * 128;
  int kBase = blockIdx.z * kLen;

  f32x4 acc[4][4];
#pragma unroll
  for (int i = 0; i < 4; i++)
#pragma unroll
    for (int j = 0; j < 4; j++){ acc[i][j][0]=0.f; acc[i][j][1]=0.f; acc[i][j][2]=0.f; acc[i][j][3]=0.f; }

  int nk = kLen >> 5;
  for (int kt = 0; kt < nk; kt++){
    int k0 = kBase + (kt << 5);
#pragma unroll
    for (int i = 0; i < 2; i++){
      int cidx = tid + i * 256;
      int row = cidx >> 2, kc = (cidx & 3) << 3;
      *(uint4*)&As[row * 32 + kc] = *(const uint4*)&A[(size_t)(m0 + row) * lda + k0 + kc];
      int br = n0 + row; if (br >= N) br = N - 1;
      *(uint4*)&Bs[row * 32 + kc] = *(const uint4*)&B[(size_t)br * ldb + k0 + kc];
    }
    __syncthreads();
    bf16x8 af[4], bfv[4];
#pragma unroll
    for (int i = 0; i < 4; i++)
      af[i] = *(const bf16x8*)&As[((w >> 1) * 64 + i * 16 + lm) * 32 + qd * 8];
#pragma unroll
    for (int j = 0; j < 4; j++)
      bfv[j] = *(const bf16x8*)&Bs[((w & 1) * 64 + j * 16 + lm) * 32 + qd * 8];
#pragma unroll
    for (int i = 0; i < 4; i++)
#pragma unroll
      for (int j = 0; j < 4; j++)
        acc[i][j] = __builtin_amdgcn_mfma_f32_16x16x32_bf16(af[i], bfv[j], acc[i][j], 0, 0, 0);
    __syncthreads();
  }

#pragma unroll
  for (int i = 0; i < 4; i++){
    int mBase = m0 + (w >> 1) * 64 + i * 16 + qd * 4;
#pragma unroll
    for (int j = 0; j < 4; j++){
      int n = n0 + (w & 1) * 64 + j * 16 + lm;
      if (n < N){
#pragma unroll
        for (int rr = 0; rr < 4; rr++){
          float val = acc[i][j][rr];
          int mm = mBase + rr;
          if (MODE == 1){
            int proj = mm >> 11, o = mm & 2047, hh = o >> 8, d = o & 255;
            int bh = (n / 400) * 8 + hh, tt = n % 400;
            unsigned short* dst = (proj == 0) ? qb : ((proj == 1) ? kb : vb);
            dst[((size_t)bh * 400 + tt) * 256 + d] = f2bf(val);
          } else {
            outf[(size_t)blockIdx.z * M * N + (size_t)n * M + mm] = val;
          }
        }
      }
    }
  }
}

// ---------------------------------------------------------------------------
// TTT persistent kernel. 256 WGs: 16 heads x 16 INNER-slices (64 wide).
// Z2 allreduce: fp32 atomicAdd partials, reduced-value readback (R7 scheme).
// LDS layout (ushort offsets; all b128 bases 8-aligned):
// ---------------------------------------------------------------------------
#define O_W1BT 0        // [64][264]  W1^T bf16 (inner, hd)
#define O_W2K  16896    // [64][264]  W2 bf16   (inner, hd)  - B for gZ1
#define O_W2N  33792    // [256][72]  W2^T bf16 (hd, inner)  - B for Z2
#define O_XKQ  52224    // [10][264]  xk bf16
#define O_TGT  54864    // [10][256]  (xv-xk) bf16
#define O_A1   57424    // [10][72]   A1 bf16
#define O_A1T  58144    // [64][32]   A1^T bf16, XOR-swizzled (cols>=10 zero - REQUIRED)
#define O_GZ2  60192    // [10][264]  gZ2 bf16
#define O_GZ1  62832    // [64][32]   gZ1 bf16, XOR-swizzled (cols>=10 zero - REQUIRED)
#define O_XQ2  64880    // [10][264]  xq bf16 (prev chunk's xq during fill)
#define O_GZ2T 67520    // [256][24]  gZ2^T bf16 (cols>=10 zero)
#define O_XKT  73664    // [256][24]  xk^T bf16
#define O_A1Q  79808    // [10][72]   A1q bf16 (fill phase)
#define O_F32  80528    // floats: b1s[64], b2[256]
#define O_GW   81168    // bf16[256]
#define O_GB   81424    // bf16[256]
#define US_TOTAL 81680
#define TTT_LDS_BYTES (81680 * 2)   // 163360 <= 163840

// XOR swizzle for the stride-32us [64][32] tiles: spreads the 16B fragment
// blocks of rows r, r+4, ... across all 8 bank-quads (was 4x overhead).
#define A1T_IDX(r, c) (O_A1T + ((((r) * 32) + (c)) ^ (((r) & 3) << 3)))
#define GZ1_IDX(r, c) (O_GZ1 + ((((r) * 32) + (c)) ^ (((r) & 3) << 3)))

#define ETA 0.01f
#define BAR_STRIDE 32   // 128B per head counter

__global__ __launch_bounds__(256, 1) void k_ttt(
    const unsigned short* __restrict__ qg, const unsigned short* __restrict__ kg,
    const unsigned short* __restrict__ vg,
    const float* __restrict__ W1g, const float* __restrict__ b1g,
    const float* __restrict__ W2g, const float* __restrict__ b2g,
    const float* __restrict__ gwg, const float* __restrict__ gbg,
    float* __restrict__ z2acc, unsigned short* __restrict__ zqp,
    unsigned int* __restrict__ bar)
{
  extern __shared__ unsigned short lds[];
  float* ldsf = (float*)&lds[O_F32];

  int tid = threadIdx.x, w = tid >> 6, l = tid & 63, qd = l >> 4, lm = l & 15;
  int bid = blockIdx.x;
  int jj = bid >> 3, xx = bid & 7;
  int h  = xx + 8 * (jj >> 4);   // bh = b*8 + head  (0..15)
  int sl = jj & 15;              // INNER slice (0..15)
  int hh = h & 7;

  for (int i = tid; i < US_TOTAL; i += 256) lds[i] = 0;
  __syncthreads();

  float w1r[4][4][4];
#pragma unroll
  for (int a = 0; a < 4; a++)
#pragma unroll
    for (int nt = 0; nt < 4; nt++)
#pragma unroll
      for (int rr = 0; rr < 4; rr++)
        w1r[a][nt][rr] = W1g[((size_t)hh * 256 + (4 * w + a) * 16 + qd * 4 + rr) * 1024
                             + sl * 64 + nt * 16 + lm];
  float w2r[16][4];
#pragma unroll
  for (int nt = 0; nt < 16; nt++)
#pragma unroll
    for (int rr = 0; rr < 4; rr++)
      w2r[nt][rr] = W2g[((size_t)hh * 1024 + sl * 64 + w * 16 + qd * 4 + rr) * 256
                        + nt * 16 + lm];
  if (tid < 64)  ldsf[tid] = b1g[hh * 1024 + sl * 64 + tid];
  if (tid < 256){
    ldsf[64 + tid] = b2g[hh * 256 + tid];
    lds[O_GW + tid] = f2bf(gwg[hh * 256 + tid]);
    lds[O_GB + tid] = f2bf(gbg[hh * 256 + tid]);
  }

#define WRITE_W1BF() do { \
  _Pragma("unroll") for (int a = 0; a < 4; a++){ \
    int m0i = (4 * w + a) * 16 + qd * 4; \
    _Pragma("unroll") for (int nt = 0; nt < 4; nt++){ \
      int n = nt * 16 + lm; \
      unsigned int p0 = f2bf(w1r[a][nt][0]) | ((unsigned int)f2bf(w1r[a][nt][1]) << 16); \
      unsigned int p1 = f2bf(w1r[a][nt][2]) | ((unsigned int)f2bf(w1r[a][nt][3]) << 16); \
      *(unsigned int*)&lds[O_W1BT + n * 264 + m0i]     = p0; \
      *(unsigned int*)&lds[O_W1BT + n * 264 + m0i + 2] = p1; \
    } } } while(0)

#define WRITE_W2BF() do { \
  int mB = w * 16 + qd * 4; \
  _Pragma("unroll") for (int nt = 0; nt < 16; nt++){ \
    int n = nt * 16 + lm; \
    _Pragma("unroll") for (int rr = 0; rr < 4; rr++) \
      lds[O_W2K + (mB + rr) * 264 + n] = f2bf(w2r[nt][rr]); \
    unsigned int p0 = f2bf(w2r[nt][0]) | ((unsigned int)f2bf(w2r[nt][1]) << 16); \
    unsigned int p1 = f2bf(w2r[nt][2]) | ((unsigned int)f2bf(w2r[nt][3]) << 16); \
    *(unsigned int*)&lds[O_W2N + n * 72 + mB]     = p0; \
    *(unsigned int*)&lds[O_W2N + n * 72 + mB + 2] = p1; \
  } } while(0)

  const size_t hb2 = (size_t)h * 400 * 256;

  unsigned int kreg[5], vreg[5];

#define LOAD_XK_REGS(NCH) do { \
  const unsigned int* kp = (const unsigned int*)(kg + hb2 + (size_t)(NCH) * 2560); \
  const unsigned int* vp = (const unsigned int*)(vg + hb2 + (size_t)(NCH) * 2560); \
  _Pragma("unroll") for (int i5 = 0; i5 < 5; i5++){ \
    kreg[i5] = kp[i5 * 256 + tid]; \
    vreg[i5] = vp[i5 * 256 + tid]; \
  } } while(0)

#define COMMIT_XK_TGT() do { \
  _Pragma("unroll") for (int i5 = 0; i5 < 5; i5++){ \
    int f2i = i5 * 256 + tid; \
    unsigned int ku = kreg[i5], vu = vreg[i5]; \
    int row = f2i >> 7, col = (f2i & 127) * 2; \
    *(unsigned int*)&lds[O_XKQ + row * 264 + col] = ku; \
    lds[O_XKT + col * 24 + row]       = (unsigned short)(ku & 0xffffu); \
    lds[O_XKT + (col + 1) * 24 + row] = (unsigned short)(ku >> 16); \
    float kv0 = bf2f((unsigned short)(ku & 0xffffu)), kv1 = bf2f((unsigned short)(ku >> 16)); \
    float vv0 = bf2f((unsigned short)(vu & 0xffffu)), vv1 = bf2f((unsigned short)(vu >> 16)); \
    unsigned int tu = (unsigned int)f2bf(vv0 - kv0) | ((unsigned int)f2bf(vv1 - kv1) << 16); \
    *(unsigned int*)&lds[O_TGT + row * 256 + col] = tu; \
  } } while(0)

#define LOAD_XQ(NCH) do { \
  const unsigned int* qp = (const unsigned int*)(qg + hb2 + (size_t)(NCH) * 2560); \
  _Pragma("unroll") for (int i5 = 0; i5 < 5; i5++){ \
    int f2i = i5 * 256 + tid; \
    unsigned int qu = qp[f2i]; \
    int row = f2i >> 7, col = (f2i & 127) * 2; \
    *(unsigned int*)&lds[O_XQ2 + row * 264 + col] = qu; \
  } } while(0)

  WRITE_W1BF();
  WRITE_W2BF();
  LOAD_XK_REGS(0);
  COMMIT_XK_TGT();
  LOAD_XQ(0);
  __syncthreads();

  for (int nch = 0; nch < 40; nch++){
    const size_t chunkBase = (size_t)(h * 40 + nch) * 10 * 256;

    // W1^T / b1 fragments for this chunk's weights (reused by the query fill)
    bf16x8 w1f[8];
#pragma unroll
    for (int ks = 0; ks < 8; ks++)
      w1f[ks] = *(const bf16x8*)&lds[O_W1BT + (w * 16 + lm) * 264 + ks * 32 + qd * 8];
    float b1n = ldsf[w * 16 + lm];

    // 1. Z1 = xk@W1 + b1 -> A1 (uses W_{nch-1})
    f32x4 z1a; z1a[0]=0.f; z1a[1]=0.f; z1a[2]=0.f; z1a[3]=0.f;
#pragma unroll
    for (int ks = 0; ks < 8; ks++){
      bf16x8 av = *(const bf16x8*)&lds[O_XKQ + lm * 264 + ks * 32 + qd * 8];
      z1a = __builtin_amdgcn_mfma_f32_16x16x32_bf16(av, w1f[ks], z1a, 0, 0, 0);
    }
    float z1v[4];
#pragma unroll
    for (int rr = 0; rr < 4; rr++){
      z1v[rr] = z1a[rr] + b1n;
      int mr = qd * 4 + rr;
      if (mr < 10){
        float a1 = gelu_f(z1v[rr]);
        unsigned short ab = f2bf(a1);
        lds[O_A1 + mr * 72 + w * 16 + lm] = ab;
        lds[A1T_IDX(w * 16 + lm, mr)] = ab;
      }
    }
    __syncthreads();

    // 3. Z2 partial = A1@W2 -> fp32 atomicAdd into per-chunk accumulator
    bf16x8 a1f[2], w2f[4][2];
#pragma unroll
    for (int ks = 0; ks < 2; ks++)
      a1f[ks] = *(const bf16x8*)&lds[O_A1 + lm * 72 + ks * 32 + qd * 8];
#pragma unroll
    for (int nt4 = 0; nt4 < 4; nt4++)
#pragma unroll
      for (int ks = 0; ks < 2; ks++)
        w2f[nt4][ks] = *(const bf16x8*)&lds[O_W2N + ((4 * w + nt4) * 16 + lm) * 72 + ks * 32 + qd * 8];

#pragma unroll
    for (int nt4 = 0; nt4 < 4; nt4++){
      int nt = 4 * w + nt4;
      f32x4 p; p[0]=0.f; p[1]=0.f; p[2]=0.f; p[3]=0.f;
#pragma unroll
      for (int ks = 0; ks < 2; ks++)
        p = __builtin_amdgcn_mfma_f32_16x16x32_bf16(a1f[ks], w2f[nt4][ks], p, 0, 0, 0);
#pragma unroll
      for (int rr = 0; rr < 4; rr++){
        int mr = qd * 4 + rr;
        if (mr < 10)
          aadd(&z2acc[chunkBase + (size_t)mr * 256 + nt * 16 + lm], p[rr]);
      }
    }
    __syncthreads();   // drain atomics (release)

    // 5. barrier add, then FILL the wait slot with prev chunk's query outputs
    if (tid == 0)
      __hip_atomic_fetch_add(bar + h * BAR_STRIDE, 1u, __ATOMIC_RELAXED, __HIP_MEMORY_SCOPE_AGENT);

    // issue next chunk's xk/xv global loads early (commit to LDS much later)
    if (nch + 1 < 40)
      LOAD_XK_REGS(nch + 1);

    if (nch > 0){
      // Z1q_{nch-1} = xq_{nch-1}@W1_{nch-1} + b1_{nch-1} -> A1q  (w1f = W_{nch-1})
      f32x4 zq; zq[0]=0.f; zq[1]=0.f; zq[2]=0.f; zq[3]=0.f;
#pragma unroll
      for (int ks = 0; ks < 8; ks++){
        bf16x8 av = *(const bf16x8*)&lds[O_XQ2 + lm * 264 + ks * 32 + qd * 8];
        zq = __builtin_amdgcn_mfma_f32_16x16x32_bf16(av, w1f[ks], zq, 0, 0, 0);
      }
#pragma unroll
      for (int rr = 0; rr < 4; rr++){
        int mr = qd * 4 + rr;
        if (mr < 10)
          lds[O_A1Q + mr * 72 + w * 16 + lm] = f2bf(gelu_f(zq[rr] + b1n));
      }
    }
    __syncthreads();   // A1Q visible; XQ2 free

    if (nch > 0){
      LOAD_XQ(nch);    // overwrite with current chunk's xq (for next fill)
      // Z2q partial = A1q@W2_{nch-1} -> bf16 store (chunk nch-1); w2f reused
      unsigned short* zq_out = zqp + ((size_t)(h * 16 + sl) * 40 + (nch - 1)) * 2560;
      bf16x8 a1qf[2];
#pragma unroll
      for (int ks = 0; ks < 2; ks++)
        a1qf[ks] = *(const bf16x8*)&lds[O_A1Q + lm * 72 + ks * 32 + qd * 8];
#pragma unroll
      for (int nt4 = 0; nt4 < 4; nt4++){
        int nt = 4 * w + nt4;
        f32x4 p; p[0]=0.f; p[1]=0.f; p[2]=0.f; p[3]=0.f;
#pragma unroll
        for (int ks = 0; ks < 2; ks++)
          p = __builtin_amdgcn_mfma_f32_16x16x32_bf16(a1qf[ks], w2f[nt4][ks], p, 0, 0, 0);
        float bb = (sl == 0) ? ldsf[64 + nt * 16 + lm] : 0.f;
#pragma unroll
        for (int rr = 0; rr < 4; rr++){
          int mr = qd * 4 + rr;
          if (mr < 10)
            zq_out[mr * 256 + nt * 16 + lm] = f2bf(p[rr] + bb);
        }
      }
    }

    // 6. poll (after fill — wait time absorbed by the fill work above)
    if (tid == 0){
      unsigned int target = 16u * (unsigned int)(nch + 1);
      unsigned int spins = 0;
      while (__hip_atomic_load(bar + h * BAR_STRIDE, __ATOMIC_RELAXED, __HIP_MEMORY_SCOPE_AGENT) < target
             && spins < 8000000u){ spins++; __builtin_amdgcn_s_sleep(1); }
    }
    __syncthreads();

    // 7. gZ2 (fused LN-L2 backward) from reduced Z2, redundantly per WG
    for (int r2 = w; r2 < 10; r2 += 4){
      int c0 = l * 4;
      const float* bp = &z2acc[chunkBase + (size_t)r2 * 256 + c0];
      float2 u01 = aload2(bp);
      float2 u23 = aload2(bp + 2);
      float zz[4] = {u01.x, u01.y, u23.x, u23.y};
      float s1 = 0.f, s2 = 0.f;
#pragma unroll
      for (int i = 0; i < 4; i++){ zz[i] += ldsf[64 + c0 + i]; s1 += zz[i]; s2 += zz[i] * zz[i]; }
#pragma unroll
      for (int off = 32; off >= 1; off >>= 1){ s1 += __shfl_xor(s1, off, 64); s2 += __shfl_xor(s2, off, 64); }
      float mu = s1 * (1.f / 256.f);
      float var = s2 * (1.f / 256.f) - mu * mu;
      float rstd = rsqrtf(var + 1e-6f);
      float xh[4], gx[4];
      float t1 = 0.f, t2 = 0.f;
#pragma unroll
      for (int i = 0; i < 4; i++){
        xh[i] = (zz[i] - mu) * rstd;
        float gwv = bf2f(lds[O_GW + c0 + i]), gbv = bf2f(lds[O_GB + c0 + i]);
        float tg = bf2f(lds[O_TGT + r2 * 256 + c0 + i]);
        float go = gwv * xh[i] + gbv - tg;
        gx[i] = go * gwv;
        t1 += gx[i]; t2 += gx[i] * xh[i];
      }
#pragma unroll
      for (int off = 32; off >= 1; off >>= 1){ t1 += __shfl_xor(t1, off, 64); t2 += __shfl_xor(t2, off, 64); }
      float m1 = t1 * (1.f / 256.f), m2 = t2 * (1.f / 256.f);
      float g0 = (gx[0] - m1 - xh[0] * m2) * rstd;
      float g1 = (gx[1] - m1 - xh[1] * m2) * rstd;
      float g2 = (gx[2] - m1 - xh[2] * m2) * rstd;
      float g3 = (gx[3] - m1 - xh[3] * m2) * rstd;
      unsigned int p0 = f2bf(g0) | ((unsigned int)f2bf(g1) << 16);
      unsigned int p1 = f2bf(g2) | ((unsigned int)f2bf(g3) << 16);
      *(unsigned int*)&lds[O_GZ2 + r2 * 264 + c0]     = p0;
      *(unsigned int*)&lds[O_GZ2 + r2 * 264 + c0 + 2] = p1;
    }
    __syncthreads();

    // 9a. b2 -= eta * sum_rows(gZ2); build gZ2^T
    {
      float sum = 0.f;
#pragma unroll
      for (int r2 = 0; r2 < 10; r2++){
        unsigned short g = lds[O_GZ2 + r2 * 264 + tid];
        lds[O_GZ2T + tid * 24 + r2] = g;
        sum += bf2f(g);
      }
      ldsf[64 + tid] -= ETA * sum;
    }
    // 9b. gZ1 = (gZ2 @ W2^T) * gelu'(Z1)
    {
      f32x4 g1a; g1a[0]=0.f; g1a[1]=0.f; g1a[2]=0.f; g1a[3]=0.f;
#pragma unroll
      for (int ks = 0; ks < 8; ks++){
        bf16x8 av = *(const bf16x8*)&lds[O_GZ2 + lm * 264 + ks * 32 + qd * 8];
        bf16x8 bv = *(const bf16x8*)&lds[O_W2K + (w * 16 + lm) * 264 + ks * 32 + qd * 8];
        g1a = __builtin_amdgcn_mfma_f32_16x16x32_bf16(av, bv, g1a, 0, 0, 0);
      }
#pragma unroll
      for (int rr = 0; rr < 4; rr++){
        int mr = qd * 4 + rr;
        if (mr < 10){
          float gz1 = g1a[rr] * gelu_bwd_f(z1v[rr]);
          lds[GZ1_IDX(w * 16 + lm, mr)] = f2bf(gz1);
        }
      }
    }
    __syncthreads();

    // 11a. b1 -= eta * colsum(gZ1)
    if (tid < 64){
      float sum = 0.f;
#pragma unroll
      for (int kx = 0; kx < 10; kx++) sum += bf2f(lds[GZ1_IDX(tid, kx)]);
      ldsf[tid] -= ETA * sum;
    }
    // 11b. W1 update: dW1 = xk^T @ gZ1
#pragma unroll
    for (int a = 0; a < 4; a++){
      int mt = 4 * w + a;
      bf16x8 av = *(const bf16x8*)&lds[O_XKT + (mt * 16 + lm) * 24 + (qd & 1) * 8];
#pragma unroll
      for (int nt = 0; nt < 4; nt++){
        bf16x8 bv = *(const bf16x8*)&lds[GZ1_IDX(nt * 16 + lm, qd * 8)];
        f32x4 d; d[0]=0.f; d[1]=0.f; d[2]=0.f; d[3]=0.f;
        d = __builtin_amdgcn_mfma_f32_16x16x32_bf16(av, bv, d, 0, 0, 0);
#pragma unroll
        for (int rr = 0; rr < 4; rr++) w1r[a][nt][rr] -= ETA * d[rr];
      }
    }
    // 11c. W2 update: dW2 = A1^T @ gZ2
    {
      bf16x8 av2 = *(const bf16x8*)&lds[A1T_IDX(w * 16 + lm, qd * 8)];
#pragma unroll
      for (int nt = 0; nt < 16; nt++){
        bf16x8 bv = *(const bf16x8*)&lds[O_GZ2T + (nt * 16 + lm) * 24 + (qd & 1) * 8];
        f32x4 d; d[0]=0.f; d[1]=0.f; d[2]=0.f; d[3]=0.f;
        d = __builtin_amdgcn_mfma_f32_16x16x32_bf16(av2, bv, d, 0, 0, 0);
#pragma unroll
        for (int rr = 0; rr < 4; rr++) w2r[nt][rr] -= ETA * d[rr];
      }
    }
    WRITE_W1BF();
    WRITE_W2BF();
    __syncthreads();

    // commit next chunk's xk/tgt (loads were issued back in the wait slot)
    if (nch + 1 < 40){
      COMMIT_XK_TGT();
    }
    __syncthreads();
  }

  // epilogue: query outputs for chunk 39 (W1BT/W2N = W_39, XQ2 = xq_39)
  {
    f32x4 zq; zq[0]=0.f; zq[1]=0.f; zq[2]=0.f; zq[3]=0.f;
#pragma unroll
    for (int ks = 0; ks < 8; ks++){
      bf16x8 av = *(const bf16x8*)&lds[O_XQ2 + lm * 264 + ks * 32 + qd * 8];
      bf16x8 bv = *(const bf16x8*)&lds[O_W1BT + (w * 16 + lm) * 264 + ks * 32 + qd * 8];
      zq = __builtin_amdgcn_mfma_f32_16x16x32_bf16(av, bv, zq, 0, 0, 0);
    }
    float b1n = ldsf[w * 16 + lm];
#pragma unroll
    for (int rr = 0; rr < 4; rr++){
      int mr = qd * 4 + rr;
      if (mr < 10)
        lds[O_A1Q + mr * 72 + w * 16 + lm] = f2bf(gelu_f(zq[rr] + b1n));
    }
  }
  __syncthreads();
  {
    unsigned short* zq_out = zqp + ((size_t)(h * 16 + sl) * 40 + 39) * 2560;
#pragma unroll
    for (int nt4 = 0; nt4 < 4; nt4++){
      int nt = 4 * w + nt4;
      f32x4 p; p[0]=0.f; p[1]=0.f; p[2]=0.f; p[3]=0.f;
#pragma unroll
      for (int ks = 0; ks < 2; ks++){
        bf16x8 av = *(const bf16x8*)&lds[O_A1Q + lm * 72 + ks * 32 + qd * 8];
        bf16x8 bv = *(const bf16x8*)&lds[O_W2N + (nt * 16 + lm) * 72 + ks * 32 + qd * 8];
        p = __builtin_amdgcn_mfma_f32_16x16x32_bf16(av, bv, p, 0, 0, 0);
      }
      float bb = (sl == 0) ? ldsf[64 + nt * 16 + lm] : 0.f;
#pragma unroll
      for (int rr = 0; rr < 4; rr++){
        int mr = qd * 4 + rr;
        if (mr < 10)
          zq_out[mr * 256 + nt * 16 + lm] = f2bf(p[rr] + bb);
      }
    }
  }
}

// ---------------------------------------------------------------------------
// LN forward + residual; sums 16 bf16 slice partials of Z2q in fp32.
// ---------------------------------------------------------------------------
__global__ __launch_bounds__(256) void k_lnout(
    const unsigned short* __restrict__ zqp, const unsigned short* __restrict__ qg,
    const float* __restrict__ gwg, const float* __restrict__ gbg,
    unsigned short* __restrict__ obf)
{
  int w = threadIdx.x >> 6, l = threadIdx.x & 63;
  int gr = blockIdx.x * 4 + w;
  int h = gr / 400, t = gr % 400, hh = h & 7, b = h >> 3;
  int nch = t / 10, mr = t % 10;
  int c0 = l * 4;
  float z[4] = {0.f, 0.f, 0.f, 0.f};
#pragma unroll
  for (int sl = 0; sl < 16; sl++){
    const unsigned short* zp = zqp + (((size_t)(h * 16 + sl) * 40 + nch) * 10 + mr) * 256 + c0;
    ushort4 u = *(const ushort4*)zp;
    z[0] += bf2f(u.x); z[1] += bf2f(u.y); z[2] += bf2f(u.z); z[3] += bf2f(u.w);
  }
  float s1 = 0.f, s2 = 0.f;
#pragma unroll
  for (int i = 0; i < 4; i++){ s1 += z[i]; s2 += z[i] * z[i]; }
#pragma unroll
  for (int off = 32; off >= 1; off >>= 1){ s1 += __shfl_xor(s1, off, 64); s2 += __shfl_xor(s2, off, 64); }
  float mu = s1 * (1.f / 256.f);
  float var = s2 * (1.f / 256.f) - mu * mu;
  float rstd = rsqrtf(var + 1e-6f);
  const unsigned short* qp = &qg[((size_t)h * 400 + t) * 256];
  ushort4 qu = *(const ushort4*)&qp[c0];
  float qv[4] = {bf2f(qu.x), bf2f(qu.y), bf2f(qu.z), bf2f(qu.w)};
  unsigned short* op = &obf[((size_t)(b * 400 + t)) * 2048 + hh * 256];
#pragma unroll
  for (int i = 0; i < 4; i++){
    float xh = (z[i] - mu) * rstd;
    float o = qv[i] + gwg[hh * 256 + c0 + i] * xh + gbg[hh * 256 + c0 + i];
    op[c0 + i] = f2bf(o);
  }
}

// ---------------------------------------------------------------------------
// launch — workspace map (bytes)
// ---------------------------------------------------------------------------
#define WS_WEFF   0u          // weff (dead after gemm0) | zqp 52.4MB | g2part 26.2MB (post-lnout)
#define WS_P      31719424u
#define WS_WQKV   44109824u
#define WS_WOB    52428800u
#define WS_Z2ACC  62722048u   // fp32 Z2 per-chunk accumulator (6.55MB)
#define WS_XB     69275648u
#define WS_Q      72552448u   // | g0part 13.1MB (pre-gemm1)
#define WS_K      75829248u
#define WS_V      79106048u
#define WS_OBF    82382848u
#define WS_BSUM   85659648u
#define WS_BAR    85667840u

extern "C" void kernel_launch(void* const* d_in, const int* in_sizes, int n_in,
                              void* d_out, int out_size, void* d_ws, size_t ws_size,
                              hipStream_t stream)
{
  (void)in_sizes; (void)n_in; (void)out_size; (void)ws_size;
  const float* x  = (const float*)d_in[0];
  const float* cw[6]; const float* cb[6];
  for (int i = 0; i < 6; i++){ cw[i] = (const float*)d_in[2 + 2 * i]; cb[i] = (const float*)d_in[3 + 2 * i]; }
  const float* wq  = (const float*)d_in[14];
  const float* wk  = (const float*)d_in[15];
  const float* wv  = (const float*)d_in[16];
  const float* wo  = (const float*)d_in[17];
  const float* W1  = (const float*)d_in[18];
  const float* b1  = (const float*)d_in[19];
  const float* W2  = (const float*)d_in[20];
  const float* b2  = (const float*)d_in[21];
  const float* lnw = (const float*)d_in[22];
  const float* lnb = (const float*)d_in[23];
  float* outf = (float*)d_out;

  char* wsb = (char*)d_ws;
  unsigned short* weff = (unsigned short*)(wsb + WS_WEFF);
  unsigned short* P    = (unsigned short*)(wsb + WS_P);
  unsigned short* wqkv = (unsigned short*)(wsb + WS_WQKV);
  unsigned short* wob  = (unsigned short*)(wsb + WS_WOB);
  unsigned short* xb   = (unsigned short*)(wsb + WS_XB);
  unsigned short* qb   = (unsigned short*)(wsb + WS_Q);
  unsigned short* kb   = (unsigned short*)(wsb + WS_K);
  unsigned short* vb   = (unsigned short*)(wsb + WS_V);
  float* z2acc = (float*)(wsb + WS_Z2ACC);
  unsigned short* zqp = (unsigned short*)(wsb + WS_WEFF);
  unsigned short* obf = (unsigned short*)(wsb + WS_OBF);
  float* bsum = (float*)(wsb + WS_BSUM);
  unsigned int* bar = (unsigned int*)(wsb + WS_BAR);
  float* g0part = (float*)(wsb + WS_Q);      // pre-gemm1
  float* g2part = (float*)(wsb + WS_WEFF);   // post-lnout (zqp dead), 26.2MB

  hipMemsetAsync(bar, 0, 16 * BAR_STRIDE * 4, stream);
  hipFuncSetAttribute(reinterpret_cast<const void*>(k_ttt),
                      hipFuncAttributeMaxDynamicSharedMemorySize, TTT_LDS_BYTES);
  hipFuncSetAttribute(reinterpret_cast<const void*>(k_weff),
                      hipFuncAttributeMaxDynamicSharedMemorySize, 18304 * 4);

  k_weff<<<2048, 256, 18304 * 4, stream>>>(cw[0], cw[1], cw[2], cw[3], cw[4], cw[5],
                                           cb[0], cb[1], cb[2], cb[3], cb[4], cb[5],
                                           weff, bsum);
  k_im2col<<<(800 * 7744 + 255) / 256, 256, 0, stream>>>(x, P);
  k_wqkv<<<(6144 * 2048 + 255) / 256, 256, 0, stream>>>(wq, wk, wv, wqkv);

  k_gemm<2><<<dim3(16, 7, 2), 256, 0, stream>>>(weff, P, 2048, 800, 7744, 7744, 3872,
                                                nullptr, nullptr, nullptr, g0part);
  k_comb_silu<<<1600, 256, 0, stream>>>(g0part, g0part + 1638400, bsum, xb);

  k_gemm<1><<<dim3(48, 7, 1), 256, 0, stream>>>(wqkv, xb, 6144, 800, 2048, 2048, 2048,
                                                qb, kb, vb, nullptr);

  k_f2bf_copy<<<(2048 * 2048 + 255) / 256, 256, 0, stream>>>(wo, wob, 2048 * 2048);
  hipMemsetAsync(z2acc, 0, 16 * 40 * 10 * 256 * 4, stream);

  k_ttt<<<256, 256, TTT_LDS_BYTES, stream>>>(qb, kb, vb, W1, b1, W2, b2, lnw, lnb,
                                             z2acc, zqp, bar);
  k_lnout<<<1600, 256, 0, stream>>>(zqp, qb, lnw, lnb, obf);

  k_gemm<2><<<dim3(16, 7, 4), 256, 0, stream>>>(wob, obf, 2048, 800, 2048, 2048, 512,
                                                nullptr, nullptr, nullptr, g2part);
  k_comb_add4<<<1600, 256, 0, stream>>>(g2part, outf);
}